// Round 10
// baseline (335.677 us; speedup 1.0000x reference)
//
#include <hip/hip_runtime.h>

// Attention_Layer: scores=d@e^T -> softmax -> value=attn@e -> tanh([value,d]@W+b)
// B=8 TE=4096 TD=1024 H=256 NH=256, f32 in/out.
// Round 10: flash5's EXACT memory system (grid 512x512thr, dbuf gload_lds STAGE,
// row-major globals, 96KB LDS, 1 blk/CU) + 32x32x16 MFMA via iteration-parity
// wave pairs: waves (pa, pa+4) share a 32-q tile; wave p computes s-tiles with
// it&1==p; split-softmax partials merged once at the end in LDS.

#define B_ 8
#define TE_ 4096
#define TD_ 1024
#define H_ 256
#define NS_ 8
#define CHUNK_ (TE_ / NS_)   // 512
#define NIT_ (CHUNK_ / 32)   // 16
#define NROW_ (B_ * TD_)     // 8192

typedef __attribute__((ext_vector_type(8))) short s16x8;
typedef __attribute__((ext_vector_type(4))) float fx4;
typedef __attribute__((ext_vector_type(16))) float fx16;
typedef __attribute__((ext_vector_type(4))) unsigned short u16x4;

#define MFMA32(a, b, c) __builtin_amdgcn_mfma_f32_32x32x16_bf16(a, b, c, 0, 0, 0)

__device__ __forceinline__ unsigned short f2bf(float x) {
  unsigned u = __float_as_uint(x);
  unsigned r = (u + 0x7fffu + ((u >> 16) & 1u)) >> 16;  // RNE
  return (unsigned short)r;
}
__device__ __forceinline__ float bf2f(unsigned short s) {
  return __uint_as_float(((unsigned)s) << 16);
}
__device__ __forceinline__ unsigned pk2(float f0, float f1) {
  return (__float_as_uint(f0) >> 16) | (__float_as_uint(f1) & 0xFFFF0000u);
}
__device__ __forceinline__ void gload_lds16(const void* g, void* l) {
  __builtin_amdgcn_global_load_lds(
      (const __attribute__((address_space(1))) void*)g,
      (__attribute__((address_space(3))) void*)l, 16, 0, 0);
}

// ---------------- prep: e -> ehi(RNE)/elo(resid) [b][TE][H], eT [b][H][TE];
//                  W -> WT bf16 [256n][512k]   (flash5-era verbatim, proven)
__global__ __launch_bounds__(256) void prep(const float* __restrict__ e,
                                            const float* __restrict__ W,
                                            unsigned short* __restrict__ ehi,
                                            unsigned short* __restrict__ elo,
                                            unsigned short* __restrict__ eT,
                                            unsigned short* __restrict__ WT) {
  __shared__ unsigned short lt[64][65];
  __shared__ float wl[32][33];
  const int bid = blockIdx.x;
  const int tid = threadIdx.x;
  if (bid < 2048) {                   // e part: 8 * 64 * 4 tiles
    const int b = bid >> 8;
    const int s0 = ((bid >> 2) & 63) * 64;
    const int h0 = (bid & 3) * 64;
#pragma unroll
    for (int i = 0; i < 4; ++i) {
      const int row = (tid >> 4) + 16 * i;
      const int col = (tid & 15) * 4;
      const size_t go = (((size_t)b * TE_) + s0 + row) * H_ + h0 + col;
      const fx4 v = *(const fx4*)&e[go];
      u16x4 hv, lv;
#pragma unroll
      for (int j = 0; j < 4; ++j) {
        const unsigned short hb = f2bf(v[j]);
        hv[j] = hb;
        lv[j] = f2bf(v[j] - bf2f(hb));
        lt[row][col + j] = hb;
      }
      *(u16x4*)&ehi[go] = hv;
      *(u16x4*)&elo[go] = lv;
    }
    __syncthreads();
#pragma unroll
    for (int i = 0; i < 2; ++i) {
      const int idx = tid + 256 * i;
      const int hh = idx >> 3;
      const int sc = (idx & 7) * 8;
      s16x8 v;
#pragma unroll
      for (int j = 0; j < 8; ++j) v[j] = (short)lt[sc + j][hh];
      *(s16x8*)&eT[(((size_t)b * H_) + h0 + hh) * TE_ + s0 + sc] = v;
    }
  } else {                            // W part: 128 tiles of 32x32
    const int tb = bid - 2048;
    const int k0 = (tb >> 3) * 32, n0 = (tb & 7) * 32;
    const int r = tid >> 3, c4 = (tid & 7) * 4;
    const fx4 v = *(const fx4*)&W[(size_t)(k0 + r) * 256 + n0 + c4];
#pragma unroll
    for (int j = 0; j < 4; ++j) wl[r][c4 + j] = v[j];
    __syncthreads();
    u16x4 o;
#pragma unroll
    for (int j = 0; j < 4; ++j) o[j] = f2bf(wl[c4 + j][r]);
    *(u16x4*)&WT[(size_t)(n0 + r) * 512 + k0 + c4] = o;
  }
}

// ---------------- flash10: 512 blocks = b(8)|qb(8)|ns(8); 8 waves (4 pairs x 32q)
__global__ __launch_bounds__(512, 1) void flash10(
    const unsigned short* __restrict__ ehi_g, const unsigned short* __restrict__ elo_g,
    const unsigned short* __restrict__ eT_g, const float* __restrict__ dmat,
    unsigned short* __restrict__ pacc, float* __restrict__ pm,
    float* __restrict__ pl) {
  const int bid = blockIdx.x;
  const int ns = bid & 7;             // flash5-proven mapping
  const int qb = (bid >> 3) & 7;
  const int b = bid >> 6;
  const int tid = threadIdx.x;
  const int w = tid >> 6;
  const int pa = w & 3;               // pair id (SIMD id)
  const int p = w >> 2;               // parity within pair
  const int lane = tid & 63;
  const int ln = lane & 31, hi = lane >> 5;
  const int q = qb * 128 + pa * 32 + ln;
  const size_t R = (size_t)b * TD_ + q;

  __shared__ uint4 smem[2][3][1024];  // 96 KB: dbuf x {ehi, elo, eT} (flash5 verbatim)

  // ---- staging pointers (flash5 verbatim: swizzled e source, linear eT map)
  const unsigned short *peh0, *peh1, *pel0, *pel1, *pet0, *pet1;
  {
    const size_t ebase = ((size_t)b * TE_ + ns * CHUNK_) * H_;
    const size_t tbase = (size_t)b * H_ * TE_ + ns * CHUNK_;
    int L = tid;
    int s = L >> 5, ch = L & 31;
    peh0 = ehi_g + ebase + s * H_ + (ch ^ (s & 7)) * 8;
    pel0 = elo_g + ebase + s * H_ + (ch ^ (s & 7)) * 8;
    int h2 = (L >> 6) * 16 + (L & 15), sc = ((L >> 4) & 3) * 8;
    pet0 = eT_g + tbase + (size_t)h2 * TE_ + sc;
    L = tid + 512;
    s = L >> 5; ch = L & 31;
    peh1 = ehi_g + ebase + s * H_ + (ch ^ (s & 7)) * 8;
    pel1 = elo_g + ebase + s * H_ + (ch ^ (s & 7)) * 8;
    h2 = (L >> 6) * 16 + (L & 15); sc = ((L >> 4) & 3) * 8;
    pet1 = eT_g + tbase + (size_t)h2 * TE_ + sc;
  }
  auto STAGE = [&](int buf) {
    uint4* eh = smem[buf][0];
    uint4* el = smem[buf][1];
    uint4* et = smem[buf][2];
    gload_lds16(peh0, &eh[tid]);
    gload_lds16(peh1, &eh[tid + 512]);
    gload_lds16(pel0, &el[tid]);
    gload_lds16(pel1, &el[tid + 512]);
    gload_lds16(pet0, &et[tid]);
    gload_lds16(pet1, &et[tid + 512]);
    peh0 += 32 * H_; peh1 += 32 * H_;
    pel0 += 32 * H_; pel1 += 32 * H_;
    pet0 += 32; pet1 += 32;
  };

  STAGE(0);                           // tile 0 in flight during d-preload

  // ---- d B-frags hi/lo in VGPRs (full K=256): B[k=kk*16+hi*8+j][n=q]
  s16x8 bdh[16], bdl[16];
  {
    const float* dr = dmat + R * H_ + hi * 8;
#pragma unroll
    for (int kk = 0; kk < 16; ++kk) {
      const fx4 x0 = *(const fx4*)(dr + kk * 16);
      const fx4 x1 = *(const fx4*)(dr + kk * 16 + 4);
      s16x8 hh, ll;
#pragma unroll
      for (int j = 0; j < 4; ++j) {
        unsigned short hb = f2bf(x0[j]);
        hh[j] = (short)hb; ll[j] = (short)f2bf(x0[j] - bf2f(hb));
        hb = f2bf(x1[j]);
        hh[4 + j] = (short)hb; ll[4 + j] = (short)f2bf(x1[j] - bf2f(hb));
      }
      bdh[kk] = hh; bdl[kk] = ll;
    }
  }

  fx16 acc[8];
#pragma unroll
  for (int nt = 0; nt < 8; ++nt)
#pragma unroll
    for (int r = 0; r < 16; ++r) acc[nt][r] = 0.f;
  float m = -__builtin_inff(), l = 0.f;

  const int xr = ln & 7;              // e-tile read swizzle (row = s = ln)

  __syncthreads();                    // tile 0 resident

  for (int it = 0; it < NIT_; ++it) {
    const int cur = it & 1;
    if (it + 1 < NIT_) STAGE(cur ^ 1);   // prefetch next tile (flash5 verbatim)

    if ((it & 1) == p) {              // parity split: this wave computes this s-tile
      const uint4* eA = smem[cur][0] + ln * 32;
      const uint4* eL = smem[cur][1] + ln * 32;
      // PV eT base: slot(h,cs) = (h>>4)*64 + cs*16 + (h&15); h = nt*32+ln
      const uint4* eT_b = smem[cur][2] + (ln >> 4) * 64 + (ln & 15);

      // ---- QK^T (swapped): S^T[32s][32q] = e(A, LDS) x d(B, regs); 2 chains
      fx16 saA, saB;
#pragma unroll
      for (int r = 0; r < 16; ++r) { saA[r] = 0.f; saB[r] = 0.f; }
#pragma unroll
      for (int kk = 0; kk < 16; ++kk) {
        const int sl = (kk * 2 + hi) ^ xr;
        const s16x8 ah = *(const s16x8*)(eA + sl);
        const s16x8 al = *(const s16x8*)(eL + sl);
        saA = MFMA32(ah, bdh[kk], saA);
        saB = MFMA32(al, bdh[kk], saB);
        saB = MFMA32(ah, bdl[kk], saB);
      }
      fx16 sa;
#pragma unroll
      for (int r = 0; r < 16; ++r) sa[r] = saA[r] + saB[r];

      // ---- online softmax (col q=ln: 16 regs + partner lane^32) [flash6 proven]
      float mx = sa[0];
#pragma unroll
      for (int r = 1; r < 16; ++r) mx = fmaxf(mx, sa[r]);
      mx = fmaxf(mx, __shfl_xor(mx, 32, 64));
      if (!__all(mx <= m + 4.0f)) {    // defer-max
        const float nm = fmaxf(m, mx);
        const float sc = __expf(m - nm);
        m = nm; l *= sc;
#pragma unroll
        for (int nt = 0; nt < 8; ++nt)
#pragma unroll
          for (int r = 0; r < 16; ++r) acc[nt][r] *= sc;
      }
      float t[16];
      float rs = 0.f;
#pragma unroll
      for (int r = 0; r < 16; ++r) {
        t[r] = bf2f(f2bf(__expf(sa[r] - m)));   // RNE bf16-rounded P
        rs += t[r];
      }
      rs += __shfl_xor(rs, 32, 64);
      l += rs;

      // ---- pack P^T bf16: rows (r&3)+8*(r>>2)+4*hi [flash6 proven]
      unsigned pku[2][4];
      pku[0][0] = pk2(t[0], t[1]);   pku[0][1] = pk2(t[2], t[3]);
      pku[0][2] = pk2(t[4], t[5]);   pku[0][3] = pk2(t[6], t[7]);
      pku[1][0] = pk2(t[8], t[9]);   pku[1][1] = pk2(t[10], t[11]);
      pku[1][2] = pk2(t[12], t[13]); pku[1][3] = pk2(t[14], t[15]);

      // ---- PV: value^T[h][q] += eT(A) x P^T(B); one lane^32 swap [flash6 proven]
#pragma unroll
      for (int ks = 0; ks < 2; ++ks) {
        const unsigned P0 = pku[ks][0], P1 = pku[ks][1];
        const unsigned P2 = pku[ks][2], P3 = pku[ks][3];
        const unsigned x0 = hi ? P0 : P2;
        const unsigned x1 = hi ? P1 : P3;
        const unsigned r0 = __shfl_xor(x0, 32, 64);
        const unsigned r1 = __shfl_xor(x1, 32, 64);
        union { unsigned u[4]; s16x8 v; } pf;
        pf.u[0] = hi ? r0 : P0; pf.u[1] = hi ? r1 : P1;
        pf.u[2] = hi ? P2 : r0; pf.u[3] = hi ? P3 : r1;
#pragma unroll
        for (int nt = 0; nt < 8; ++nt) {
          const s16x8 ea = *(const s16x8*)(eT_b + nt * 128 + (ks * 2 + hi) * 16);
          acc[nt] = MFMA32(ea, pf.v, acc[nt]);
        }
      }
    }
    __syncthreads();                  // drains prefetch; next tile resident
  }

  // ---- pair merge: waves (pa, pa+4) hold disjoint-s partials for same 32 q
  float* smf = (float*)smem;          // reuse LDS
  fx4* smq = (fx4*)smem;              // acc exchange region (<=64KB)
  smf[16384 + w * 64 + lane] = m;
  smf[16384 + 512 + w * 64 + lane] = l;
  __syncthreads();
  const int wp = (1 - p) * 4 + pa;    // partner wave
  const float mo = smf[16384 + wp * 64 + lane];
  const float lo2 = smf[16384 + 512 + wp * 64 + lane];
  const float M = fmaxf(m, mo);
  const float scme = __expf(m - M);
  const float l_tot = l * scme + lo2 * __expf(mo - M);
#pragma unroll
  for (int nt = 0; nt < 8; ++nt)
#pragma unroll
    for (int r = 0; r < 16; ++r) acc[nt][r] *= scme;
  __syncthreads();                    // m/l reads done before smq overwrite
  // round A: p=1 writes acc[0..3]; p=0 accumulates
  if (p == 1) {
#pragma unroll
    for (int nt = 0; nt < 4; ++nt)
#pragma unroll
      for (int qd = 0; qd < 4; ++qd) {
        fx4 qv = {acc[nt][qd * 4], acc[nt][qd * 4 + 1], acc[nt][qd * 4 + 2], acc[nt][qd * 4 + 3]};
        smq[pa * 1024 + (nt * 4 + qd) * 64 + lane] = qv;
      }
  }
  __syncthreads();
  if (p == 0) {
#pragma unroll
    for (int nt = 0; nt < 4; ++nt)
#pragma unroll
      for (int qd = 0; qd < 4; ++qd) {
        const fx4 qv = smq[pa * 1024 + (nt * 4 + qd) * 64 + lane];
#pragma unroll
        for (int j = 0; j < 4; ++j) acc[nt][qd * 4 + j] += qv[j];
      }
  }
  __syncthreads();
  // round B: p=0 writes acc[4..7]; p=1 accumulates
  if (p == 0) {
#pragma unroll
    for (int nt = 4; nt < 8; ++nt)
#pragma unroll
      for (int qd = 0; qd < 4; ++qd) {
        fx4 qv = {acc[nt][qd * 4], acc[nt][qd * 4 + 1], acc[nt][qd * 4 + 2], acc[nt][qd * 4 + 3]};
        smq[pa * 1024 + ((nt - 4) * 4 + qd) * 64 + lane] = qv;
      }
  }
  __syncthreads();
  if (p == 1) {
#pragma unroll
    for (int nt = 4; nt < 8; ++nt)
#pragma unroll
      for (int qd = 0; qd < 4; ++qd) {
        const fx4 qv = smq[pa * 1024 + ((nt - 4) * 4 + qd) * 64 + lane];
#pragma unroll
        for (int j = 0; j < 4; ++j) acc[nt][qd * 4 + j] += qv[j];
      }
  }

  // ---- row-major bf16 partials (flash6-style store; p=0 stores h<128, p=1 rest)
  unsigned short* pr = pacc + (((size_t)ns * NROW_) + R) * H_;
  const int nt0 = p * 4, nt1 = nt0 + 4;
#pragma unroll
  for (int nt = 0; nt < 8; ++nt) {
    if (nt >= nt0 && nt < nt1) {
#pragma unroll
      for (int qd = 0; qd < 4; ++qd) {
        u16x4 o;
#pragma unroll
        for (int j = 0; j < 4; ++j) o[j] = f2bf(acc[nt][qd * 4 + j]);
        *(u16x4*)(pr + nt * 32 + qd * 8 + hi * 4) = o;
      }
    }
  }
  if (p == 0 && hi == 0) {
    pm[ns * NROW_ + R] = M;
    pl[ns * NROW_ + R] = l_tot;
  }
}

// ---------------- dense2: combine NS partials -> X=[value,d] bf16 -> MFMA -> tanh
//                  (flash5-era verbatim: row-major pacc, proven)
__global__ __launch_bounds__(256) void dense2(const unsigned short* __restrict__ pacc,
                                              const float* __restrict__ pm,
                                              const float* __restrict__ pl,
                                              const float* __restrict__ dmat,
                                              const unsigned short* __restrict__ WT,
                                              const float* __restrict__ bias,
                                              float* __restrict__ out) {
  const int row0 = blockIdx.x * 32;    // 256 blocks
  const int tid = threadIdx.x;
  const int w = tid >> 6;
  const int lane = tid & 63;
  const int ln = lane & 31, hi = lane >> 5;
  __shared__ unsigned short Xl[32][520];

  {
    const int row = tid >> 3;
    const int c0 = (tid & 7) * 32;
    const int R = row0 + row;
    float wts[NS_];
    float M = -__builtin_inff();
#pragma unroll
    for (int s = 0; s < NS_; ++s) M = fmaxf(M, pm[s * NROW_ + R]);
    float L = 0.f;
#pragma unroll
    for (int s = 0; s < NS_; ++s) {
      wts[s] = __expf(pm[s * NROW_ + R] - M);
      L += wts[s] * pl[s * NROW_ + R];
    }
    const float inv = 1.0f / L;
#pragma unroll
    for (int c8 = 0; c8 < 4; ++c8) {
      const int cc = c0 + c8 * 8;
      float o8[8];
#pragma unroll
      for (int j = 0; j < 8; ++j) o8[j] = 0.f;
#pragma unroll
      for (int s = 0; s < NS_; ++s) {
        const s16x8 v = *(const s16x8*)&pacc[(((size_t)s * NROW_) + R) * H_ + cc];
#pragma unroll
        for (int j = 0; j < 8; ++j)
          o8[j] += wts[s] * bf2f((unsigned short)v[j]);
      }
      u16x4 y0, y1;
#pragma unroll
      for (int j = 0; j < 4; ++j) {
        y0[j] = f2bf(o8[j] * inv);
        y1[j] = f2bf(o8[4 + j] * inv);
      }
      *(u16x4*)&Xl[row][cc] = y0;
      *(u16x4*)&Xl[row][cc + 4] = y1;
    }
    const float* drow = dmat + (size_t)R * H_ + c0;
#pragma unroll
    for (int c8 = 0; c8 < 8; ++c8) {
      const fx4 v = *(const fx4*)&drow[c8 * 4];
      u16x4 y;
#pragma unroll
      for (int j = 0; j < 4; ++j) y[j] = f2bf(v[j]);
      *(u16x4*)&Xl[row][256 + c0 + c8 * 4] = y;
    }
  }
  __syncthreads();

  fx16 a0, a1;
#pragma unroll
  for (int r = 0; r < 16; ++r) { a0[r] = 0.f; a1[r] = 0.f; }
  const int n0 = w * 64;
#pragma unroll
  for (int ks = 0; ks < 32; ++ks) {
    const s16x8 av = *(const s16x8*)&Xl[ln][ks * 16 + hi * 8];
    const s16x8 b0 = *(const s16x8*)(WT + (size_t)(n0 + ln) * 512 + ks * 16 + hi * 8);
    const s16x8 b1 = *(const s16x8*)(WT + (size_t)(n0 + 32 + ln) * 512 + ks * 16 + hi * 8);
    a0 = MFMA32(av, b0, a0);
    a1 = MFMA32(av, b1, a1);
  }
  const float bn0 = bias[n0 + ln];
  const float bn1 = bias[n0 + 32 + ln];
#pragma unroll
  for (int r = 0; r < 16; ++r) {
    const int rloc = (r & 3) + 8 * (r >> 2) + 4 * hi;
    const size_t ro = (size_t)(row0 + rloc) * 256;
    out[ro + n0 + ln] = tanhf(a0[r] + bn0);
    out[ro + n0 + 32 + ln] = tanhf(a1[r] + bn1);
  }
}

extern "C" void kernel_launch(void* const* d_in, const int* in_sizes, int n_in,
                              void* d_out, int out_size, void* d_ws, size_t ws_size,
                              hipStream_t stream) {
  const float* e = (const float*)d_in[0];    // [8,4096,256]
  const float* d = (const float*)d_in[1];    // [8,1024,256]
  const float* W = (const float*)d_in[2];    // [512,256]
  const float* bias = (const float*)d_in[3]; // [256]
  float* out = (float*)d_out;

  char* p = (char*)d_ws;
  const size_t EB = (size_t)B_ * TE_ * H_ * 2;       // 16 MiB
  const size_t WB = (size_t)512 * 256 * 2;           // 256 KiB
  const size_t PB = (size_t)NS_ * NROW_ * H_ * 2;    // 32 MiB (bf16 partials)
  unsigned short* ehi = (unsigned short*)p;            p += EB;
  unsigned short* elo = (unsigned short*)p;            p += EB;
  unsigned short* eT  = (unsigned short*)p;            p += EB;
  unsigned short* WT  = (unsigned short*)p;            p += WB;
  unsigned short* pacc = (unsigned short*)p;           p += PB;
  float* pmv = (float*)p;                              p += (size_t)NS_ * NROW_ * 4;
  float* plv = (float*)p;                              // total ~80.8 MiB

  prep<<<dim3(2176), dim3(256), 0, stream>>>(e, W, ehi, elo, eT, WT);
  flash10<<<dim3(512), dim3(512), 0, stream>>>(ehi, elo, eT, d, pacc, pmv, plv);
  dense2<<<dim3(256), dim3(256), 0, stream>>>(pacc, pmv, plv, d, WT, bias, out);
}

// Round 11
// 114.927 us; speedup vs baseline: 2.9208x; 2.9208x over previous
//
#include <hip/hip_runtime.h>

// Attention_Layer: scores=d@e^T -> softmax -> value=attn@e -> tanh([value,d]@W+b)
// B=8 TE=4096 TD=1024 H=256 NH=256, f32 in/out.
// Round 11: round-5 (best: 132.5us) VERBATIM body with NS 8->4:
// 256 blocks = 1/CU in ONE dispatch round, pacc halved (16MB), d redundancy
// halved. flash/prep/dense2 instruction streams unchanged from round 5
// (96 VGPR, no spills -- the round-6..10 32x32 bodies all spilled to scratch,
// which is what exploded FETCH to 380-530MB; never exceed ~200 regs/wave).

#define B_ 8
#define TE_ 4096
#define TD_ 1024
#define H_ 256
#define NS_ 4
#define CHUNK_ (TE_ / NS_)   // 1024
#define NIT_ (CHUNK_ / 32)   // 32
#define NROW_ (B_ * TD_)     // 8192

typedef __attribute__((ext_vector_type(8))) short s16x8;
typedef __attribute__((ext_vector_type(4))) float fx4;
typedef __attribute__((ext_vector_type(16))) float fx16;
typedef __attribute__((ext_vector_type(4))) unsigned short u16x4;

#define MFMA(a, b, c) __builtin_amdgcn_mfma_f32_16x16x32_bf16(a, b, c, 0, 0, 0)
#define MFMA32(a, b, c) __builtin_amdgcn_mfma_f32_32x32x16_bf16(a, b, c, 0, 0, 0)

__device__ __forceinline__ unsigned short f2bf(float x) {
  unsigned u = __float_as_uint(x);
  unsigned r = (u + 0x7fffu + ((u >> 16) & 1u)) >> 16;  // RNE
  return (unsigned short)r;
}
__device__ __forceinline__ float bf2f(unsigned short s) {
  return __uint_as_float(((unsigned)s) << 16);
}
// pack two bf16-representable f32 into one u32 (lo = f0, hi = f1)
__device__ __forceinline__ unsigned pk2(float f0, float f1) {
  return (__float_as_uint(f0) >> 16) | (__float_as_uint(f1) & 0xFFFF0000u);
}
__device__ __forceinline__ void gload_lds16(const void* g, void* l) {
  __builtin_amdgcn_global_load_lds(
      (const __attribute__((address_space(1))) void*)g,
      (__attribute__((address_space(3))) void*)l, 16, 0, 0);
}

// ---------------- prep: e -> ehi(RNE)/elo(resid) [b][TE][H], eT [b][H][TE];
//                  W -> WT bf16 [256n][512k]   (round-5 verbatim)
__global__ __launch_bounds__(256) void prep(const float* __restrict__ e,
                                            const float* __restrict__ W,
                                            unsigned short* __restrict__ ehi,
                                            unsigned short* __restrict__ elo,
                                            unsigned short* __restrict__ eT,
                                            unsigned short* __restrict__ WT) {
  __shared__ unsigned short lt[64][65];
  __shared__ float wl[32][33];
  const int bid = blockIdx.x;
  const int tid = threadIdx.x;
  if (bid < 2048) {                   // e part: 8 * 64 * 4 tiles
    const int b = bid >> 8;
    const int s0 = ((bid >> 2) & 63) * 64;
    const int h0 = (bid & 3) * 64;
#pragma unroll
    for (int i = 0; i < 4; ++i) {
      const int row = (tid >> 4) + 16 * i;
      const int col = (tid & 15) * 4;
      const size_t go = (((size_t)b * TE_) + s0 + row) * H_ + h0 + col;
      const fx4 v = *(const fx4*)&e[go];
      u16x4 hv, lv;
#pragma unroll
      for (int j = 0; j < 4; ++j) {
        const unsigned short hb = f2bf(v[j]);
        hv[j] = hb;
        lv[j] = f2bf(v[j] - bf2f(hb));
        lt[row][col + j] = hb;
      }
      *(u16x4*)&ehi[go] = hv;
      *(u16x4*)&elo[go] = lv;
    }
    __syncthreads();
#pragma unroll
    for (int i = 0; i < 2; ++i) {
      const int idx = tid + 256 * i;
      const int hh = idx >> 3;
      const int sc = (idx & 7) * 8;
      s16x8 v;
#pragma unroll
      for (int j = 0; j < 8; ++j) v[j] = (short)lt[sc + j][hh];
      *(s16x8*)&eT[(((size_t)b * H_) + h0 + hh) * TE_ + s0 + sc] = v;
    }
  } else {                            // W part: 128 tiles of 32x32
    const int tb = bid - 2048;
    const int k0 = (tb >> 3) * 32, n0 = (tb & 7) * 32;
    const int r = tid >> 3, c4 = (tid & 7) * 4;
    const fx4 v = *(const fx4*)&W[(size_t)(k0 + r) * 256 + n0 + c4];
#pragma unroll
    for (int j = 0; j < 4; ++j) wl[r][c4 + j] = v[j];
    __syncthreads();
    u16x4 o;
#pragma unroll
    for (int j = 0; j < 4; ++j) o[j] = f2bf(wl[c4 + j][r]);
    *(u16x4*)&WT[(size_t)(n0 + r) * 512 + k0 + c4] = o;
  }
}

// ---------------- flash11: 256 blocks = b(8)|qb(8)|ns(4); 8 waves x 16 q
//                  (round-5 flash5 verbatim except grid decode / NS)
__global__ __launch_bounds__(512, 2) void flash11(
    const unsigned short* __restrict__ ehi_g, const unsigned short* __restrict__ elo_g,
    const unsigned short* __restrict__ eT_g, const float* __restrict__ dmat,
    unsigned short* __restrict__ pacc, float* __restrict__ pm,
    float* __restrict__ pl) {
  const int bid = blockIdx.x;
  const int ns = bid & 3;             // 4-way KV split; sharers on close XCDs
  const int qb = (bid >> 2) & 7;
  const int b = bid >> 5;
  const int tid = threadIdx.x;
  const int w = tid >> 6;
  const int lane = tid & 63;
  const int g = lane >> 4, c = lane & 15;
  const int qrow = qb * 128 + w * 16 + c;

  __shared__ uint4 smem[2][3][1024];  // 96 KB: dbuf x {ehi, elo, eT}

  // ---- loop-invariant staging source pointers (advance per staged tile)
  const unsigned short *peh0, *peh1, *pel0, *pel1, *pet0, *pet1;
  {
    const size_t ebase = ((size_t)b * TE_ + ns * CHUNK_) * H_;
    const size_t tbase = (size_t)b * H_ * TE_ + ns * CHUNK_;
    int L = tid;
    int s = L >> 5, ch = L & 31;
    peh0 = ehi_g + ebase + s * H_ + (ch ^ (s & 7)) * 8;
    pel0 = elo_g + ebase + s * H_ + (ch ^ (s & 7)) * 8;
    int h2 = (L >> 6) * 16 + (L & 15), sc = ((L >> 4) & 3) * 8;
    pet0 = eT_g + tbase + (size_t)h2 * TE_ + sc;
    L = tid + 512;
    s = L >> 5; ch = L & 31;
    peh1 = ehi_g + ebase + s * H_ + (ch ^ (s & 7)) * 8;
    pel1 = elo_g + ebase + s * H_ + (ch ^ (s & 7)) * 8;
    h2 = (L >> 6) * 16 + (L & 15); sc = ((L >> 4) & 3) * 8;
    pet1 = eT_g + tbase + (size_t)h2 * TE_ + sc;
  }
  auto STAGE = [&](int buf) {
    uint4* eh = smem[buf][0];
    uint4* el = smem[buf][1];
    uint4* et = smem[buf][2];
    gload_lds16(peh0, &eh[tid]);
    gload_lds16(peh1, &eh[tid + 512]);
    gload_lds16(pel0, &el[tid]);
    gload_lds16(pel1, &el[tid + 512]);
    gload_lds16(pet0, &et[tid]);
    gload_lds16(pet1, &et[tid + 512]);
    peh0 += 32 * H_; peh1 += 32 * H_;
    pel0 += 32 * H_; pel1 += 32 * H_;
    pet0 += 32; pet1 += 32;
  };

  STAGE(0);                           // tile 0 in flight during d-preload

  // ---- d B-frags hi/lo in registers (once)
  s16x8 bd_h[8], bd_l[8];
  {
    const float* dr = dmat + ((size_t)b * TD_ + qrow) * H_;
#pragma unroll
    for (int kk = 0; kk < 8; ++kk) {
      const fx4 x0 = *(const fx4*)&dr[kk * 32 + g * 8];
      const fx4 x1 = *(const fx4*)&dr[kk * 32 + g * 8 + 4];
      s16x8 hh, ll;
#pragma unroll
      for (int j = 0; j < 4; ++j) {
        unsigned short hb = f2bf(x0[j]);
        hh[j] = (short)hb; ll[j] = (short)f2bf(x0[j] - bf2f(hb));
        hb = f2bf(x1[j]);
        hh[4 + j] = (short)hb; ll[4 + j] = (short)f2bf(x1[j] - bf2f(hb));
      }
      bd_h[kk] = hh; bd_l[kk] = ll;
    }
  }

  fx4 acc[16];
#pragma unroll
  for (int nt = 0; nt < 16; ++nt) acc[nt] = (fx4){0.f, 0.f, 0.f, 0.f};
  float m = -__builtin_inff(), l = 0.f;
  const int xr = c & 7;

  __syncthreads();                    // tile 0 resident

  for (int it = 0; it < NIT_; ++it) {
    const int cur = it & 1;
    if (it + 1 < NIT_) STAGE(cur ^ 1);   // prefetch next tile (drained at barrier)

    const uint4* eh = smem[cur][0];
    const uint4* el = smem[cur][1];
    const uint4* et = smem[cur][2];

    // ---- QK^T (swapped): S^T[s][q] = e(A, LDS) x d(B, regs), 3-term hi/lo
    fx4 sa0 = (fx4){0.f, 0.f, 0.f, 0.f};
    fx4 sa1 = (fx4){0.f, 0.f, 0.f, 0.f};
#pragma unroll
    for (int kk = 0; kk < 8; ++kk) {
      const int sl = (kk * 4 + g) ^ xr;
      const s16x8 ah0 = *(const s16x8*)&eh[c * 32 + sl];
      const s16x8 al0 = *(const s16x8*)&el[c * 32 + sl];
      const s16x8 ah1 = *(const s16x8*)&eh[(16 + c) * 32 + sl];
      const s16x8 al1 = *(const s16x8*)&el[(16 + c) * 32 + sl];
      sa0 = MFMA(ah0, bd_h[kk], sa0);
      sa0 = MFMA(al0, bd_h[kk], sa0);
      sa0 = MFMA(ah0, bd_l[kk], sa0);
      sa1 = MFMA(ah1, bd_h[kk], sa1);
      sa1 = MFMA(al1, bd_h[kk], sa1);
      sa1 = MFMA(ah1, bd_l[kk], sa1);
    }

    // ---- online softmax (q=c lives on 4 g-lanes: 2 shfl rounds)
    float mx = fmaxf(fmaxf(fmaxf(sa0[0], sa0[1]), fmaxf(sa0[2], sa0[3])),
                     fmaxf(fmaxf(sa1[0], sa1[1]), fmaxf(sa1[2], sa1[3])));
    mx = fmaxf(mx, __shfl_xor(mx, 16, 64));
    mx = fmaxf(mx, __shfl_xor(mx, 32, 64));
    if (!__all(mx <= m + 4.0f)) {      // defer-max
      const float nm = fmaxf(m, mx);
      const float sc = __expf(m - nm);
      m = nm; l *= sc;
#pragma unroll
      for (int nt = 0; nt < 16; ++nt) {
#pragma unroll
        for (int r = 0; r < 4; ++r) acc[nt][r] *= sc;
      }
    }
    float t0[4], t1[4];
    float rs = 0.f;
#pragma unroll
    for (int r = 0; r < 4; ++r) {
      t0[r] = bf2f(f2bf(__expf(sa0[r] - m)));   // RNE bf16-rounded P
      t1[r] = bf2f(f2bf(__expf(sa1[r] - m)));
      rs += t0[r] + t1[r];                      // l matches bf16 P exactly
    }
    rs += __shfl_xor(rs, 16, 64);
    rs += __shfl_xor(rs, 32, 64);
    l += rs;

    // ---- pack P^T bf16, gather PV B-frags via shfl (validated layout)
    const unsigned pk00 = pk2(t0[0], t0[1]);
    const unsigned pk01 = pk2(t0[2], t0[3]);
    const unsigned pk10 = pk2(t1[0], t1[1]);
    const unsigned pk11 = pk2(t1[2], t1[3]);
    const int src0 = ((g & 1) << 5) + c;
    const int src1 = src0 + 16;
    const unsigned a0 = __shfl(pk00, src0, 64);
    const unsigned a1 = __shfl(pk01, src0, 64);
    const unsigned a2 = __shfl(pk00, src1, 64);
    const unsigned a3 = __shfl(pk01, src1, 64);
    const unsigned b0 = __shfl(pk10, src0, 64);
    const unsigned b1 = __shfl(pk11, src0, 64);
    const unsigned b2 = __shfl(pk10, src1, 64);
    const unsigned b3 = __shfl(pk11, src1, 64);
    const bool hiT = (g >= 2);
    union { unsigned u[4]; s16x8 v; } pb;
    pb.u[0] = hiT ? b0 : a0; pb.u[1] = hiT ? b1 : a1;
    pb.u[2] = hiT ? b2 : a2; pb.u[3] = hiT ? b3 : a3;

    // ---- PV: value^T[h][q] += eT(A, [nt][g][c] layout) x P^T(B)
#pragma unroll
    for (int nt = 0; nt < 16; ++nt) {
      const s16x8 ea = *(const s16x8*)&et[nt * 64 + g * 16 + c];
      acc[nt] = MFMA(ea, pb.v, acc[nt]);
    }
    __syncthreads();                  // drains prefetch; next tile resident
  }

  // ---- bf16 partials (unnormalized) + (m,l) per q
  const size_t R = (size_t)b * TD_ + qrow;
  unsigned short* pr = pacc + (((size_t)ns * NROW_) + R) * H_;
#pragma unroll
  for (int nt = 0; nt < 16; ++nt) {
    u16x4 o;
#pragma unroll
    for (int j = 0; j < 4; ++j) o[j] = f2bf(acc[nt][j]);
    *(u16x4*)(pr + nt * 16 + g * 4) = o;
  }
  if (g == 0) {
    pm[ns * NROW_ + R] = m;
    pl[ns * NROW_ + R] = l;
  }
}

// ---------------- dense2: combine NS partials -> X=[value,d] bf16 -> MFMA -> tanh
//                  (round-5 verbatim; NS_ loops now 4)
__global__ __launch_bounds__(256) void dense2(const unsigned short* __restrict__ pacc,
                                              const float* __restrict__ pm,
                                              const float* __restrict__ pl,
                                              const float* __restrict__ dmat,
                                              const unsigned short* __restrict__ WT,
                                              const float* __restrict__ bias,
                                              float* __restrict__ out) {
  const int row0 = blockIdx.x * 32;    // 256 blocks
  const int tid = threadIdx.x;
  const int w = tid >> 6;
  const int lane = tid & 63;
  const int ln = lane & 31, hi = lane >> 5;
  __shared__ unsigned short Xl[32][520];

  {
    const int row = tid >> 3;
    const int c0 = (tid & 7) * 32;
    const int R = row0 + row;
    float wts[NS_];
    float M = -__builtin_inff();
#pragma unroll
    for (int s = 0; s < NS_; ++s) M = fmaxf(M, pm[s * NROW_ + R]);
    float L = 0.f;
#pragma unroll
    for (int s = 0; s < NS_; ++s) {
      wts[s] = __expf(pm[s * NROW_ + R] - M);
      L += wts[s] * pl[s * NROW_ + R];
    }
    const float inv = 1.0f / L;
#pragma unroll
    for (int c8 = 0; c8 < 4; ++c8) {
      const int cc = c0 + c8 * 8;
      float o8[8];
#pragma unroll
      for (int j = 0; j < 8; ++j) o8[j] = 0.f;
#pragma unroll
      for (int s = 0; s < NS_; ++s) {
        const s16x8 v = *(const s16x8*)&pacc[(((size_t)s * NROW_) + R) * H_ + cc];
#pragma unroll
        for (int j = 0; j < 8; ++j)
          o8[j] += wts[s] * bf2f((unsigned short)v[j]);
      }
      u16x4 y0, y1;
#pragma unroll
      for (int j = 0; j < 4; ++j) {
        y0[j] = f2bf(o8[j] * inv);
        y1[j] = f2bf(o8[4 + j] * inv);
      }
      *(u16x4*)&Xl[row][cc] = y0;
      *(u16x4*)&Xl[row][cc + 4] = y1;
    }
    const float* drow = dmat + (size_t)R * H_ + c0;
#pragma unroll
    for (int c8 = 0; c8 < 8; ++c8) {
      const fx4 v = *(const fx4*)&drow[c8 * 4];
      u16x4 y;
#pragma unroll
      for (int j = 0; j < 4; ++j) y[j] = f2bf(v[j]);
      *(u16x4*)&Xl[row][256 + c0 + c8 * 4] = y;
    }
  }
  __syncthreads();

  fx16 a0, a1;
#pragma unroll
  for (int r = 0; r < 16; ++r) { a0[r] = 0.f; a1[r] = 0.f; }
  const int n0 = w * 64;
#pragma unroll
  for (int ks = 0; ks < 32; ++ks) {
    const s16x8 av = *(const s16x8*)&Xl[ln][ks * 16 + hi * 8];
    const s16x8 b0 = *(const s16x8*)(WT + (size_t)(n0 + ln) * 512 + ks * 16 + hi * 8);
    const s16x8 b1 = *(const s16x8*)(WT + (size_t)(n0 + 32 + ln) * 512 + ks * 16 + hi * 8);
    a0 = MFMA32(av, b0, a0);
    a1 = MFMA32(av, b1, a1);
  }
  const float bn0 = bias[n0 + ln];
  const float bn1 = bias[n0 + 32 + ln];
#pragma unroll
  for (int r = 0; r < 16; ++r) {
    const int rloc = (r & 3) + 8 * (r >> 2) + 4 * hi;
    const size_t ro = (size_t)(row0 + rloc) * 256;
    out[ro + n0 + ln] = tanhf(a0[r] + bn0);
    out[ro + n0 + 32 + ln] = tanhf(a1[r] + bn1);
  }
}

extern "C" void kernel_launch(void* const* d_in, const int* in_sizes, int n_in,
                              void* d_out, int out_size, void* d_ws, size_t ws_size,
                              hipStream_t stream) {
  const float* e = (const float*)d_in[0];    // [8,4096,256]
  const float* d = (const float*)d_in[1];    // [8,1024,256]
  const float* W = (const float*)d_in[2];    // [512,256]
  const float* bias = (const float*)d_in[3]; // [256]
  float* out = (float*)d_out;

  char* p = (char*)d_ws;
  const size_t EB = (size_t)B_ * TE_ * H_ * 2;       // 16 MiB
  const size_t WB = (size_t)512 * 256 * 2;           // 256 KiB
  const size_t PB = (size_t)NS_ * NROW_ * H_ * 2;    // 16 MiB (bf16 partials)
  unsigned short* ehi = (unsigned short*)p;            p += EB;
  unsigned short* elo = (unsigned short*)p;            p += EB;
  unsigned short* eT  = (unsigned short*)p;            p += EB;
  unsigned short* WT  = (unsigned short*)p;            p += WB;
  unsigned short* pacc = (unsigned short*)p;           p += PB;
  float* pmv = (float*)p;                              p += (size_t)NS_ * NROW_ * 4;
  float* plv = (float*)p;                              // total ~64.6 MiB

  prep<<<dim3(2176), dim3(256), 0, stream>>>(e, W, ehi, elo, eT, WT);
  flash11<<<dim3(256), dim3(512), 0, stream>>>(ehi, elo, eT, d, pacc, pmv, plv);
  dense2<<<dim3(256), dim3(256), 0, stream>>>(pacc, pmv, plv, d, WT, bias, out);
}

// Round 12
// 98.232 us; speedup vs baseline: 3.4172x; 1.1700x over previous
//
#include <hip/hip_runtime.h>

// Attention_Layer: scores=d@e^T -> softmax -> value=attn@e -> tanh([value,d]@W+b)
// B=8 TE=4096 TD=1024 H=256 NH=256, f32 in/out.
// Round 12: round-11 skeleton (best: 114.9us, proven L2 reuse + no spills)
// switched from bf16 to FP16 (10-bit mantissa; all data N(0,1)-ish fits):
// - QK 2-term: S = eh.dh + eh.dl (e rounded once to fp16, d exact in-register)
//   -> elo array DELETED: staged bytes/iter 48->32KB, LDS reads 48->32/wave-iter
// - P, pacc, X, WT all fp16 (8x finer rounding than bf16)
// Same grid (256 blocks, 8 waves x 16q, NS=4), same STAGE/swizzles/shfl paths.

#define B_ 8
#define TE_ 4096
#define TD_ 1024
#define H_ 256
#define NS_ 4
#define CHUNK_ (TE_ / NS_)   // 1024
#define NIT_ (CHUNK_ / 32)   // 32
#define NROW_ (B_ * TD_)     // 8192

typedef __attribute__((ext_vector_type(8))) short s16x8;
typedef __attribute__((ext_vector_type(8))) _Float16 h16x8;
typedef __attribute__((ext_vector_type(4))) float fx4;
typedef __attribute__((ext_vector_type(16))) float fx16;
typedef __attribute__((ext_vector_type(4))) unsigned short u16x4;

__device__ __forceinline__ h16x8 as_h(s16x8 v) {
  union { s16x8 s; h16x8 h; } u; u.s = v; return u.h;
}
#define MFMA(a, b, c) __builtin_amdgcn_mfma_f32_16x16x32_f16(as_h(a), as_h(b), c, 0, 0, 0)
#define MFMA32(a, b, c) __builtin_amdgcn_mfma_f32_32x32x16_f16(as_h(a), as_h(b), c, 0, 0, 0)

__device__ __forceinline__ unsigned short f2h(float x) {
  const _Float16 h = (_Float16)x;    // RNE
  union { _Float16 h; unsigned short s; } u; u.h = h; return u.s;
}
__device__ __forceinline__ float h2f(unsigned short s) {
  union { unsigned short s; _Float16 h; } u; u.s = s; return (float)u.h;
}
// pack two f32 into one u32 of 2 fp16 (lo = f0, hi = f1)
__device__ __forceinline__ unsigned pk2h(float f0, float f1) {
  return (unsigned)f2h(f0) | ((unsigned)f2h(f1) << 16);
}
__device__ __forceinline__ void gload_lds16(const void* g, void* l) {
  __builtin_amdgcn_global_load_lds(
      (const __attribute__((address_space(1))) void*)g,
      (__attribute__((address_space(3))) void*)l, 16, 0, 0);
}

// ---------------- prep: e -> eh fp16 [b][TE][H], eT fp16 [b][H][TE];
//                  W -> WT fp16 [256n][512k]
__global__ __launch_bounds__(256) void prep(const float* __restrict__ e,
                                            const float* __restrict__ W,
                                            unsigned short* __restrict__ eh,
                                            unsigned short* __restrict__ eT,
                                            unsigned short* __restrict__ WT) {
  __shared__ unsigned short lt[64][65];
  __shared__ float wl[32][33];
  const int bid = blockIdx.x;
  const int tid = threadIdx.x;
  if (bid < 2048) {                   // e part: 8 * 64 * 4 tiles
    const int b = bid >> 8;
    const int s0 = ((bid >> 2) & 63) * 64;
    const int h0 = (bid & 3) * 64;
#pragma unroll
    for (int i = 0; i < 4; ++i) {
      const int row = (tid >> 4) + 16 * i;
      const int col = (tid & 15) * 4;
      const size_t go = (((size_t)b * TE_) + s0 + row) * H_ + h0 + col;
      const fx4 v = *(const fx4*)&e[go];
      u16x4 hv;
#pragma unroll
      for (int j = 0; j < 4; ++j) {
        const unsigned short hb = f2h(v[j]);
        hv[j] = hb;
        lt[row][col + j] = hb;
      }
      *(u16x4*)&eh[go] = hv;
    }
    __syncthreads();
#pragma unroll
    for (int i = 0; i < 2; ++i) {
      const int idx = tid + 256 * i;
      const int hh = idx >> 3;
      const int sc = (idx & 7) * 8;
      s16x8 v;
#pragma unroll
      for (int j = 0; j < 8; ++j) v[j] = (short)lt[sc + j][hh];
      *(s16x8*)&eT[(((size_t)b * H_) + h0 + hh) * TE_ + s0 + sc] = v;
    }
  } else {                            // W part: 128 tiles of 32x32
    const int tb = bid - 2048;
    const int k0 = (tb >> 3) * 32, n0 = (tb & 7) * 32;
    const int r = tid >> 3, c4 = (tid & 7) * 4;
    const fx4 v = *(const fx4*)&W[(size_t)(k0 + r) * 256 + n0 + c4];
#pragma unroll
    for (int j = 0; j < 4; ++j) wl[r][c4 + j] = v[j];
    __syncthreads();
    u16x4 o;
#pragma unroll
    for (int j = 0; j < 4; ++j) o[j] = f2h(wl[c4 + j][r]);
    *(u16x4*)&WT[(size_t)(n0 + r) * 512 + k0 + c4] = o;
  }
}

// ---------------- flash12: 256 blocks = b(8)|qb(8)|ns(4); 8 waves x 16 q
__global__ __launch_bounds__(512, 2) void flash12(
    const unsigned short* __restrict__ eh_g, const unsigned short* __restrict__ eT_g,
    const float* __restrict__ dmat,
    unsigned short* __restrict__ pacc, float* __restrict__ pm,
    float* __restrict__ pl) {
  const int bid = blockIdx.x;
  const int ns = bid & 3;             // 4-way KV split (round-11 proven mapping)
  const int qb = (bid >> 2) & 7;
  const int b = bid >> 5;
  const int tid = threadIdx.x;
  const int w = tid >> 6;
  const int lane = tid & 63;
  const int g = lane >> 4, c = lane & 15;
  const int qrow = qb * 128 + w * 16 + c;

  __shared__ uint4 smem[2][2][1024];  // 64 KB: dbuf x {eh, eT}

  // ---- loop-invariant staging source pointers (round-11 mapping, minus elo)
  const unsigned short *peh0, *peh1, *pet0, *pet1;
  {
    const size_t ebase = ((size_t)b * TE_ + ns * CHUNK_) * H_;
    const size_t tbase = (size_t)b * H_ * TE_ + ns * CHUNK_;
    int L = tid;
    int s = L >> 5, ch = L & 31;
    peh0 = eh_g + ebase + s * H_ + (ch ^ (s & 7)) * 8;
    int h2 = (L >> 6) * 16 + (L & 15), sc = ((L >> 4) & 3) * 8;
    pet0 = eT_g + tbase + (size_t)h2 * TE_ + sc;
    L = tid + 512;
    s = L >> 5; ch = L & 31;
    peh1 = eh_g + ebase + s * H_ + (ch ^ (s & 7)) * 8;
    h2 = (L >> 6) * 16 + (L & 15); sc = ((L >> 4) & 3) * 8;
    pet1 = eT_g + tbase + (size_t)h2 * TE_ + sc;
  }
  auto STAGE = [&](int buf) {
    uint4* ehb = smem[buf][0];
    uint4* etb = smem[buf][1];
    gload_lds16(peh0, &ehb[tid]);
    gload_lds16(peh1, &ehb[tid + 512]);
    gload_lds16(pet0, &etb[tid]);
    gload_lds16(pet1, &etb[tid + 512]);
    peh0 += 32 * H_; peh1 += 32 * H_;
    pet0 += 32; pet1 += 32;
  };

  STAGE(0);                           // tile 0 in flight during d-preload

  // ---- d B-frags hi/lo fp16 in registers (d exact: dh + dl)
  s16x8 bd_h[8], bd_l[8];
  {
    const float* dr = dmat + ((size_t)b * TD_ + qrow) * H_;
#pragma unroll
    for (int kk = 0; kk < 8; ++kk) {
      const fx4 x0 = *(const fx4*)&dr[kk * 32 + g * 8];
      const fx4 x1 = *(const fx4*)&dr[kk * 32 + g * 8 + 4];
      s16x8 hh, ll;
#pragma unroll
      for (int j = 0; j < 4; ++j) {
        unsigned short hb = f2h(x0[j]);
        hh[j] = (short)hb; ll[j] = (short)f2h(x0[j] - h2f(hb));
        hb = f2h(x1[j]);
        hh[4 + j] = (short)hb; ll[4 + j] = (short)f2h(x1[j] - h2f(hb));
      }
      bd_h[kk] = hh; bd_l[kk] = ll;
    }
  }

  fx4 acc[16];
#pragma unroll
  for (int nt = 0; nt < 16; ++nt) acc[nt] = (fx4){0.f, 0.f, 0.f, 0.f};
  float m = -__builtin_inff(), l = 0.f;
  const int xr = c & 7;

  __syncthreads();                    // tile 0 resident

  for (int it = 0; it < NIT_; ++it) {
    const int cur = it & 1;
    if (it + 1 < NIT_) STAGE(cur ^ 1);   // prefetch next tile (drained at barrier)

    const uint4* ehb = smem[cur][0];
    const uint4* etb = smem[cur][1];

    // ---- QK^T (swapped): S^T[s][q] = eh(A, LDS) x d(B, regs), 2-term fp16
    fx4 sa0 = (fx4){0.f, 0.f, 0.f, 0.f};
    fx4 sa1 = (fx4){0.f, 0.f, 0.f, 0.f};
#pragma unroll
    for (int kk = 0; kk < 8; ++kk) {
      const int sl = (kk * 4 + g) ^ xr;
      const s16x8 ah0 = *(const s16x8*)&ehb[c * 32 + sl];
      const s16x8 ah1 = *(const s16x8*)&ehb[(16 + c) * 32 + sl];
      sa0 = MFMA(ah0, bd_h[kk], sa0);
      sa0 = MFMA(ah0, bd_l[kk], sa0);
      sa1 = MFMA(ah1, bd_h[kk], sa1);
      sa1 = MFMA(ah1, bd_l[kk], sa1);
    }

    // ---- online softmax (q=c lives on 4 g-lanes: 2 shfl rounds)
    float mx = fmaxf(fmaxf(fmaxf(sa0[0], sa0[1]), fmaxf(sa0[2], sa0[3])),
                     fmaxf(fmaxf(sa1[0], sa1[1]), fmaxf(sa1[2], sa1[3])));
    mx = fmaxf(mx, __shfl_xor(mx, 16, 64));
    mx = fmaxf(mx, __shfl_xor(mx, 32, 64));
    if (!__all(mx <= m + 4.0f)) {      // defer-max
      const float nm = fmaxf(m, mx);
      const float sc = __expf(m - nm);
      m = nm; l *= sc;
#pragma unroll
      for (int nt = 0; nt < 16; ++nt) {
#pragma unroll
        for (int r = 0; r < 4; ++r) acc[nt][r] *= sc;
      }
    }
    float t0[4], t1[4];
    float rs = 0.f;
#pragma unroll
    for (int r = 0; r < 4; ++r) {
      t0[r] = h2f(f2h(__expf(sa0[r] - m)));   // RNE fp16-rounded P
      t1[r] = h2f(f2h(__expf(sa1[r] - m)));
      rs += t0[r] + t1[r];                    // l matches fp16 P exactly
    }
    rs += __shfl_xor(rs, 16, 64);
    rs += __shfl_xor(rs, 32, 64);
    l += rs;

    // ---- pack P^T fp16, gather PV B-frags via shfl (round-11 layout)
    const unsigned pk00 = pk2h(t0[0], t0[1]);
    const unsigned pk01 = pk2h(t0[2], t0[3]);
    const unsigned pk10 = pk2h(t1[0], t1[1]);
    const unsigned pk11 = pk2h(t1[2], t1[3]);
    const int src0 = ((g & 1) << 5) + c;
    const int src1 = src0 + 16;
    const unsigned a0 = __shfl(pk00, src0, 64);
    const unsigned a1 = __shfl(pk01, src0, 64);
    const unsigned a2 = __shfl(pk00, src1, 64);
    const unsigned a3 = __shfl(pk01, src1, 64);
    const unsigned b0 = __shfl(pk10, src0, 64);
    const unsigned b1 = __shfl(pk11, src0, 64);
    const unsigned b2 = __shfl(pk10, src1, 64);
    const unsigned b3 = __shfl(pk11, src1, 64);
    const bool hiT = (g >= 2);
    union { unsigned u[4]; s16x8 v; } pb;
    pb.u[0] = hiT ? b0 : a0; pb.u[1] = hiT ? b1 : a1;
    pb.u[2] = hiT ? b2 : a2; pb.u[3] = hiT ? b3 : a3;

    // ---- PV: value^T[h][q] += eT(A, [nt][g][c] layout) x P^T(B)
#pragma unroll
    for (int nt = 0; nt < 16; ++nt) {
      const s16x8 ea = *(const s16x8*)&etb[nt * 64 + g * 16 + c];
      acc[nt] = MFMA(ea, pb.v, acc[nt]);
    }
    __syncthreads();                  // drains prefetch; next tile resident
  }

  // ---- fp16 partials (unnormalized) + (m,l) per q
  const size_t R = (size_t)b * TD_ + qrow;
  unsigned short* pr = pacc + (((size_t)ns * NROW_) + R) * H_;
#pragma unroll
  for (int nt = 0; nt < 16; ++nt) {
    u16x4 o;
#pragma unroll
    for (int j = 0; j < 4; ++j) o[j] = f2h(acc[nt][j]);
    *(u16x4*)(pr + nt * 16 + g * 4) = o;
  }
  if (g == 0) {
    pm[ns * NROW_ + R] = m;
    pl[ns * NROW_ + R] = l;
  }
}

// ---------------- dense2: combine NS partials -> X=[value,d] fp16 -> MFMA -> tanh
__global__ __launch_bounds__(256) void dense2(const unsigned short* __restrict__ pacc,
                                              const float* __restrict__ pm,
                                              const float* __restrict__ pl,
                                              const float* __restrict__ dmat,
                                              const unsigned short* __restrict__ WT,
                                              const float* __restrict__ bias,
                                              float* __restrict__ out) {
  const int row0 = blockIdx.x * 32;    // 256 blocks
  const int tid = threadIdx.x;
  const int w = tid >> 6;
  const int lane = tid & 63;
  const int ln = lane & 31, hi = lane >> 5;
  __shared__ unsigned short Xl[32][520];

  {
    const int row = tid >> 3;
    const int c0 = (tid & 7) * 32;
    const int R = row0 + row;
    float wts[NS_];
    float M = -__builtin_inff();
#pragma unroll
    for (int s = 0; s < NS_; ++s) M = fmaxf(M, pm[s * NROW_ + R]);
    float L = 0.f;
#pragma unroll
    for (int s = 0; s < NS_; ++s) {
      wts[s] = __expf(pm[s * NROW_ + R] - M);
      L += wts[s] * pl[s * NROW_ + R];
    }
    const float inv = 1.0f / L;
#pragma unroll
    for (int c8 = 0; c8 < 4; ++c8) {
      const int cc = c0 + c8 * 8;
      float o8[8];
#pragma unroll
      for (int j = 0; j < 8; ++j) o8[j] = 0.f;
#pragma unroll
      for (int s = 0; s < NS_; ++s) {
        const s16x8 v = *(const s16x8*)&pacc[(((size_t)s * NROW_) + R) * H_ + cc];
#pragma unroll
        for (int j = 0; j < 8; ++j)
          o8[j] += wts[s] * h2f((unsigned short)v[j]);
      }
      u16x4 y0, y1;
#pragma unroll
      for (int j = 0; j < 4; ++j) {
        y0[j] = f2h(o8[j] * inv);
        y1[j] = f2h(o8[4 + j] * inv);
      }
      *(u16x4*)&Xl[row][cc] = y0;
      *(u16x4*)&Xl[row][cc + 4] = y1;
    }
    const float* drow = dmat + (size_t)R * H_ + c0;
#pragma unroll
    for (int c8 = 0; c8 < 8; ++c8) {
      const fx4 v = *(const fx4*)&drow[c8 * 4];
      u16x4 y;
#pragma unroll
      for (int j = 0; j < 4; ++j) y[j] = f2h(v[j]);
      *(u16x4*)&Xl[row][256 + c0 + c8 * 4] = y;
    }
  }
  __syncthreads();

  fx16 a0, a1;
#pragma unroll
  for (int r = 0; r < 16; ++r) { a0[r] = 0.f; a1[r] = 0.f; }
  const int n0 = w * 64;
#pragma unroll
  for (int ks = 0; ks < 32; ++ks) {
    const s16x8 av = *(const s16x8*)&Xl[ln][ks * 16 + hi * 8];
    const s16x8 b0 = *(const s16x8*)(WT + (size_t)(n0 + ln) * 512 + ks * 16 + hi * 8);
    const s16x8 b1 = *(const s16x8*)(WT + (size_t)(n0 + 32 + ln) * 512 + ks * 16 + hi * 8);
    a0 = MFMA32(av, b0, a0);
    a1 = MFMA32(av, b1, a1);
  }
  const float bn0 = bias[n0 + ln];
  const float bn1 = bias[n0 + 32 + ln];
#pragma unroll
  for (int r = 0; r < 16; ++r) {
    const int rloc = (r & 3) + 8 * (r >> 2) + 4 * hi;
    const size_t ro = (size_t)(row0 + rloc) * 256;
    out[ro + n0 + ln] = tanhf(a0[r] + bn0);
    out[ro + n0 + 32 + ln] = tanhf(a1[r] + bn1);
  }
}

extern "C" void kernel_launch(void* const* d_in, const int* in_sizes, int n_in,
                              void* d_out, int out_size, void* d_ws, size_t ws_size,
                              hipStream_t stream) {
  const float* e = (const float*)d_in[0];    // [8,4096,256]
  const float* d = (const float*)d_in[1];    // [8,1024,256]
  const float* W = (const float*)d_in[2];    // [512,256]
  const float* bias = (const float*)d_in[3]; // [256]
  float* out = (float*)d_out;

  char* p = (char*)d_ws;
  const size_t EB = (size_t)B_ * TE_ * H_ * 2;       // 16 MiB
  const size_t WB = (size_t)512 * 256 * 2;           // 256 KiB
  const size_t PB = (size_t)NS_ * NROW_ * H_ * 2;    // 16 MiB (fp16 partials)
  unsigned short* eh  = (unsigned short*)p;            p += EB;
  unsigned short* eT  = (unsigned short*)p;            p += EB;
  unsigned short* WT  = (unsigned short*)p;            p += WB;
  unsigned short* pacc = (unsigned short*)p;           p += PB;
  float* pmv = (float*)p;                              p += (size_t)NS_ * NROW_ * 4;
  float* plv = (float*)p;                              // total ~48.6 MiB

  prep<<<dim3(2176), dim3(256), 0, stream>>>(e, W, eh, eT, WT);
  flash12<<<dim3(256), dim3(512), 0, stream>>>(eh, eT, d, pacc, pmv, plv);
  dense2<<<dim3(256), dim3(256), 0, stream>>>(pacc, pmv, plv, d, WT, bias, out);
}